// Round 3
// baseline (440.292 us; speedup 1.0000x reference)
//
#include <hip/hip_runtime.h>
#include <hip/hip_bf16.h>
#include <math.h>

#define BDIM 128   // batch

__device__ inline float bf2f(unsigned short u) {
    union { unsigned int i; float f; } v; v.i = ((unsigned int)u) << 16; return v.f;
}
__device__ inline unsigned short f2bf(float f) {
    union { unsigned int i; float f; } v; v.f = f;
    unsigned int x = v.i;
    return (unsigned short)((x + 0x7FFFu + ((x >> 16) & 1u)) >> 16);  // RNE
}

// ---------------- MLP encoder: x[128,4] -> M[128,2,32,32] ----
__global__ __launch_bounds__(256) void mlp_kernel(
    const float* __restrict__ x,
    const float* __restrict__ W1, const float* __restrict__ b1,
    const float* __restrict__ W2, const float* __restrict__ b2,
    const float* __restrict__ W3, const float* __restrict__ b3,
    float* __restrict__ Mout)
{
    __shared__ float h1[1024];
    __shared__ float part[8][33];
    __shared__ float h2[32];
    int b = blockIdx.x, t = threadIdx.x;
    float x0 = x[b*4+0], x1 = x[b*4+1], x2 = x[b*4+2], x3 = x[b*4+3];
#pragma unroll
    for (int q = 0; q < 4; ++q) {
        int j = t + 256*q;
        float4 w = *(const float4*)(W1 + (size_t)j*4);
        float v = x0*w.x + x1*w.y + x2*w.z + x3*w.w + b1[j];
        h1[j] = v > 0.f ? v : 0.f;
    }
    __syncthreads();
    {
        int o = t & 31, chunk = t >> 5;
        const float* w2r = W2 + (size_t)o*1024 + chunk*128;
        const float* h1r = h1 + chunk*128;
        float s = 0.f;
#pragma unroll
        for (int k = 0; k < 128; k += 4) {
            float4 w = *(const float4*)(w2r + k);
            s += h1r[k]*w.x + h1r[k+1]*w.y + h1r[k+2]*w.z + h1r[k+3]*w.w;
        }
        part[chunk][o] = s;
    }
    __syncthreads();
    if (t < 32) {
        float s = b2[t];
#pragma unroll
        for (int c = 0; c < 8; ++c) s += part[c][t];
        h2[t] = s > 0.f ? s : 0.f;
    }
    __syncthreads();
#pragma unroll
    for (int q = 0; q < 8; ++q) {
        int j = t + 256*q;
        const float* w3r = W3 + (size_t)j*32;
        float s = b3[j];
#pragma unroll
        for (int i = 0; i < 32; i += 4) {
            float4 w = *(const float4*)(w3r + i);
            s += h2[i]*w.x + h2[i+1]*w.y + h2[i+2]*w.z + h2[i+3]*w.w;
        }
        Mout[(size_t)b*2048 + j] = s;  // [b][spin][i][j]
    }
}

// ------------- one doubling level: out[b][q] = in[b][q>>1] @ M[b][q&1] ------
// IN_BF: input bf16 (else fp32). OUT_MODE: 0 fp32 plain, 1 bf16 plain,
// 2 bf16 XOR-pair layout: LL[q][((i^j)<<5)|j] = L_q[i][j]  (via LDS staging).
template<bool IN_BF, int OUT_MODE>
__global__ __launch_bounds__(256) void chain_kernel(
    const void* __restrict__ inv, const float* __restrict__ Mb,
    void* __restrict__ outv, int nq_in)
{
    int b = blockIdx.y;
    int q0 = blockIdx.x * 4;
    int nq_out = nq_in * 2;
    __shared__ float parT[2][32][36];   // parent, transposed
    __shared__ float mm[2][32][36];     // site matrices, plain
    __shared__ unsigned short stage[4][1024];  // OUT_MODE 2 staging (8KB)
    int t = threadIdx.x;
    int w = t >> 6, l = t & 63;
    if (w < 2) {
        size_t base = ((size_t)b*nq_in + (q0>>1) + w) * 1024;
#pragma unroll
        for (int r = 0; r < 4; ++r) {
            int e = r*256 + l*4;
            int row = e >> 5, c0 = e & 31;
            float v0, v1, v2, v3;
            if (IN_BF) {
                ushort4 v = *(const ushort4*)((const unsigned short*)inv + base + e);
                v0 = bf2f(v.x); v1 = bf2f(v.y); v2 = bf2f(v.z); v3 = bf2f(v.w);
            } else {
                float4 v = *(const float4*)((const float*)inv + base + e);
                v0 = v.x; v1 = v.y; v2 = v.z; v3 = v.w;
            }
            parT[w][c0+0][row] = v0; parT[w][c0+1][row] = v1;
            parT[w][c0+2][row] = v2; parT[w][c0+3][row] = v3;
        }
    } else {
        const float* src = Mb + ((size_t)b*2 + (w-2)) * 1024;
#pragma unroll
        for (int r = 0; r < 4; ++r) {
            int e = r*256 + l*4;
            float4 v = *(const float4*)(src + e);
            *(float4*)&mm[w-2][e>>5][e&31] = v;
        }
    }
    __syncthreads();
    int q = q0 + w;
    int p = w >> 1, m = w & 1;
    int r0 = (l >> 3) << 2, c0 = (l & 7) << 2;
    float acc[4][4] = {};
#pragma unroll 8
    for (int kk = 0; kk < 32; ++kk) {
        float a[4], bb[4];
        *(float4*)a  = *(const float4*)&parT[p][kk][r0];
        *(float4*)bb = *(const float4*)&mm[m][kk][c0];
#pragma unroll
        for (int i = 0; i < 4; ++i)
#pragma unroll
            for (int j = 0; j < 4; ++j)
                acc[i][j] += a[i]*bb[j];
    }
    size_t ob = ((size_t)b*nq_out + q) * 1024;
    if (OUT_MODE == 0) {
        float* dst = (float*)outv;
#pragma unroll
        for (int i = 0; i < 4; ++i) {
            float4 v = make_float4(acc[i][0], acc[i][1], acc[i][2], acc[i][3]);
            *(float4*)(dst + ob + (r0+i)*32 + c0) = v;
        }
    } else if (OUT_MODE == 1) {
        unsigned short* dst = (unsigned short*)outv;
#pragma unroll
        for (int i = 0; i < 4; ++i) {
            ushort4 v; v.x = f2bf(acc[i][0]); v.y = f2bf(acc[i][1]);
            v.z = f2bf(acc[i][2]); v.w = f2bf(acc[i][3]);
            *(ushort4*)(dst + ob + (r0+i)*32 + c0) = v;
        }
    } else {
        // scatter into XOR-pair layout in LDS, then vectorized copy out
#pragma unroll
        for (int i = 0; i < 4; ++i)
#pragma unroll
            for (int j = 0; j < 4; ++j) {
                int r = r0 + i, c = c0 + j;
                stage[w][((r ^ c) << 5) | c] = f2bf(acc[i][j]);
            }
        __syncthreads();
        unsigned short* dst = (unsigned short*)outv + ((size_t)b*256 + q0) * 1024;
        const uint4* s4 = (const uint4*)&stage[0][0];   // 512 x 16B
        uint4* d4 = (uint4*)dst;
        d4[t] = s4[t];
        d4[t + 256] = s4[t + 256];
    }
}

// ---- pairing: C_b[s][t] = Tr(L_s L_t) via LL XOR-pair layout -------------
// A[s][k]=LL[s][k]; B[t][d*32+kk]=LL[t][d*32+(kk^d)] (same-d XOR shuffle).
__global__ __launch_bounds__(256) void pair_gemm(
    const unsigned short* __restrict__ LL,
    float* __restrict__ out, float* __restrict__ norm2)
{
    int b = blockIdx.y;
    int ti = blockIdx.x >> 1, tj = blockIdx.x & 1;
    const unsigned short* Abase = LL + (size_t)b*262144 + (size_t)ti*131072;
    const unsigned short* Bbase = LL + (size_t)b*262144 + (size_t)tj*131072;
    __shared__ float As[32][132];
    __shared__ float Bs[32][132];
    int t = threadIdx.x;
    int tx = t & 15, ty = t >> 4;
    float acc[8][8] = {};
    for (int k0 = 0; k0 < 1024; k0 += 32) {
        int d = k0 >> 5;
#pragma unroll
        for (int qq = 0; qq < 4; ++qq) {
            int idx = t + 256*qq;
            int row = idx >> 3;
            int m0  = (idx & 7) << 2;
            ushort4 va = *(const ushort4*)(Abase + (size_t)row*1024 + k0 + m0);
            As[m0+0][row] = bf2f(va.x); As[m0+1][row] = bf2f(va.y);
            As[m0+2][row] = bf2f(va.z); As[m0+3][row] = bf2f(va.w);
            ushort4 vb = *(const ushort4*)(Bbase + (size_t)row*1024 + k0 + m0);
            Bs[(m0+0)^d][row] = bf2f(vb.x); Bs[(m0+1)^d][row] = bf2f(vb.y);
            Bs[(m0+2)^d][row] = bf2f(vb.z); Bs[(m0+3)^d][row] = bf2f(vb.w);
        }
        __syncthreads();
#pragma unroll 8
        for (int kk = 0; kk < 32; ++kk) {
            float a[8], bb[8];
            *(float4*)&a[0]  = *(const float4*)&As[kk][ty*8];
            *(float4*)&a[4]  = *(const float4*)&As[kk][ty*8+4];
            *(float4*)&bb[0] = *(const float4*)&Bs[kk][tx*4];        // cols tx*4..+3
            *(float4*)&bb[4] = *(const float4*)&Bs[kk][64 + tx*4];   // cols 64+tx*4..
#pragma unroll
            for (int i = 0; i < 8; ++i)
#pragma unroll
                for (int j = 0; j < 8; ++j)
                    acc[i][j] += a[i]*bb[j];
        }
        __syncthreads();
    }
    float ss = 0.f;
    size_t ob = (size_t)b*65536;
#pragma unroll
    for (int i = 0; i < 8; ++i) {
        int s = ti*128 + ty*8 + i;
        float* op = out + ob + (size_t)s*256 + tj*128;
        float4 w0 = make_float4(acc[i][0],acc[i][1],acc[i][2],acc[i][3]);
        float4 w1 = make_float4(acc[i][4],acc[i][5],acc[i][6],acc[i][7]);
        *(float4*)(op + tx*4) = w0;
        *(float4*)(op + 64 + tx*4) = w1;
#pragma unroll
        for (int j = 0; j < 8; ++j) ss += acc[i][j]*acc[i][j];
    }
#pragma unroll
    for (int o = 1; o < 64; o <<= 1) ss += __shfl_xor(ss, o);
    __shared__ float wsum[4];
    if ((t & 63) == 0) wsum[t >> 6] = ss;
    __syncthreads();
    if (t == 0) atomicAdd(norm2 + b, wsum[0]+wsum[1]+wsum[2]+wsum[3]);
}

// ---------------- normalize rows ----------------
__global__ __launch_bounds__(256) void scale_kernel(
    float* __restrict__ out, const float* __restrict__ norm2)
{
    size_t i = (size_t)blockIdx.x * 256 + threadIdx.x;  // float4 index
    int b = (int)(i >> 14);                              // 16384 float4 / row
    float s = rsqrtf(norm2[b]);
    float4 v = ((const float4*)out)[i];
    v.x *= s; v.y *= s; v.z *= s; v.w *= s;
    ((float4*)out)[i] = v;
}

extern "C" void kernel_launch(void* const* d_in, const int* in_sizes, int n_in,
                              void* d_out, int out_size, void* d_ws, size_t ws_size,
                              hipStream_t stream)
{
    (void)in_sizes; (void)n_in;
    const float* x  = (const float*)d_in[0];
    const float* W1 = (const float*)d_in[1];
    const float* b1 = (const float*)d_in[2];
    const float* W2 = (const float*)d_in[3];
    const float* b2 = (const float*)d_in[4];
    const float* W3 = (const float*)d_in[5];
    const float* b3 = (const float*)d_in[6];
    float* out = (float*)d_out;

    // ---- byte-offset workspace packing (liveness-based, peak ~117 MB) ----
    // LL  bf16 [128][256][1024] : [0, 64M)            (written by c7, read by pair)
    // X6  bf16 [128][128][1024] : [64M, 96M)          (c6 out, c7 in)
    // X5  f32  [128][ 64][1024] : [0, 32M)   (inside LL region; dead before c7)
    // X4  f32  [128][ 32][1024] : [96M, 112M)
    // X3  f32  [128][ 16][1024] : [32M, 40M) (inside LL region)
    // X2  f32  [128][  8][1024] : [112M, 116M)
    // X1  f32  [128][  4][1024] : [40M, 42M) (inside LL region)
    // M   f32  [128][  2][1024] : [116M, 117M)
    // nrm f32  [128]            : [117M, +512B)
    char* W = (char*)d_ws;
    const size_t MB = 1024*1024;
    unsigned short* LL = (unsigned short*)(W + 0);
    unsigned short* X6 = (unsigned short*)(W + 64*MB);
    float* X5 = (float*)(W + 0);
    float* X4 = (float*)(W + 96*MB);
    float* X3 = (float*)(W + 32*MB);
    float* X2 = (float*)(W + 112*MB);
    float* X1 = (float*)(W + 40*MB);
    float* Mb = (float*)(W + 116*MB);
    float* nrm = (float*)(W + 117*MB);
    const size_t NEED = 117*MB + 512;
    if (ws_size < NEED) {
        // diagnostic path: not enough scratch -> zero output (absmax-fail, no OOB)
        hipMemsetAsync(d_out, 0, (size_t)out_size * sizeof(float), stream);
        return;
    }

    hipMemsetAsync(nrm, 0, BDIM*sizeof(float), stream);
    mlp_kernel<<<BDIM, 256, 0, stream>>>(x, W1, b1, W2, b2, W3, b3, Mb);
    chain_kernel<false,0><<<dim3( 1, BDIM), 256, 0, stream>>>(Mb, Mb, X1,   2);
    chain_kernel<false,0><<<dim3( 2, BDIM), 256, 0, stream>>>(X1, Mb, X2,   4);
    chain_kernel<false,0><<<dim3( 4, BDIM), 256, 0, stream>>>(X2, Mb, X3,   8);
    chain_kernel<false,0><<<dim3( 8, BDIM), 256, 0, stream>>>(X3, Mb, X4,  16);
    chain_kernel<false,0><<<dim3(16, BDIM), 256, 0, stream>>>(X4, Mb, X5,  32);
    chain_kernel<false,1><<<dim3(32, BDIM), 256, 0, stream>>>(X5, Mb, X6,  64);
    chain_kernel<true, 2><<<dim3(64, BDIM), 256, 0, stream>>>(X6, Mb, LL, 128);
    pair_gemm<<<dim3(4, BDIM), 256, 0, stream>>>(LL, out, nrm);
    scale_kernel<<<8192, 256, 0, stream>>>(out, nrm);
}

// Round 4
// 226.392 us; speedup vs baseline: 1.9448x; 1.9448x over previous
//
#include <hip/hip_runtime.h>
#include <hip/hip_bf16.h>
#include <math.h>

#define BDIM 128   // batch

typedef short sh8 __attribute__((ext_vector_type(8)));
typedef __bf16 bf8 __attribute__((ext_vector_type(8)));
typedef float f32x4 __attribute__((ext_vector_type(4)));

__device__ inline float bf2f(unsigned short u) {
    union { unsigned int i; float f; } v; v.i = ((unsigned int)u) << 16; return v.f;
}
__device__ inline unsigned short f2bf(float f) {
    union { unsigned int i; float f; } v; v.f = f;
    unsigned int x = v.i;
    return (unsigned short)((x + 0x7FFFu + ((x >> 16) & 1u)) >> 16);  // RNE
}

// within-8 ushort XOR shuffle (compile-time folded inside unrolled loops)
__device__ inline sh8 xshuf(sh8 v, int u) {
    switch (u & 7) {
    case 0: return v;
    case 1: return __builtin_shufflevector(v,v,1,0,3,2,5,4,7,6);
    case 2: return __builtin_shufflevector(v,v,2,3,0,1,6,7,4,5);
    case 3: return __builtin_shufflevector(v,v,3,2,1,0,7,6,5,4);
    case 4: return __builtin_shufflevector(v,v,4,5,6,7,0,1,2,3);
    case 5: return __builtin_shufflevector(v,v,5,4,7,6,1,0,3,2);
    case 6: return __builtin_shufflevector(v,v,6,7,4,5,2,3,0,1);
    default: return __builtin_shufflevector(v,v,7,6,5,4,3,2,1,0);
    }
}

// ---------------- MLP encoder: x[128,4] -> M[128,2,32,32] ----
__global__ __launch_bounds__(256) void mlp_kernel(
    const float* __restrict__ x,
    const float* __restrict__ W1, const float* __restrict__ b1,
    const float* __restrict__ W2, const float* __restrict__ b2,
    const float* __restrict__ W3, const float* __restrict__ b3,
    float* __restrict__ Mout)
{
    __shared__ float h1[1024];
    __shared__ float part[8][33];
    __shared__ float h2[32];
    int b = blockIdx.x, t = threadIdx.x;
    float x0 = x[b*4+0], x1 = x[b*4+1], x2 = x[b*4+2], x3 = x[b*4+3];
#pragma unroll
    for (int q = 0; q < 4; ++q) {
        int j = t + 256*q;
        float4 w = *(const float4*)(W1 + (size_t)j*4);
        float v = x0*w.x + x1*w.y + x2*w.z + x3*w.w + b1[j];
        h1[j] = v > 0.f ? v : 0.f;
    }
    __syncthreads();
    {
        int o = t & 31, chunk = t >> 5;
        const float* w2r = W2 + (size_t)o*1024 + chunk*128;
        const float* h1r = h1 + chunk*128;
        float s = 0.f;
#pragma unroll
        for (int k = 0; k < 128; k += 4) {
            float4 w = *(const float4*)(w2r + k);
            s += h1r[k]*w.x + h1r[k+1]*w.y + h1r[k+2]*w.z + h1r[k+3]*w.w;
        }
        part[chunk][o] = s;
    }
    __syncthreads();
    if (t < 32) {
        float s = b2[t];
#pragma unroll
        for (int c = 0; c < 8; ++c) s += part[c][t];
        h2[t] = s > 0.f ? s : 0.f;
    }
    __syncthreads();
#pragma unroll
    for (int q = 0; q < 8; ++q) {
        int j = t + 256*q;
        const float* w3r = W3 + (size_t)j*32;
        float s = b3[j];
#pragma unroll
        for (int i = 0; i < 32; i += 4) {
            float4 w = *(const float4*)(w3r + i);
            s += h2[i]*w.x + h2[i+1]*w.y + h2[i+2]*w.z + h2[i+3]*w.w;
        }
        Mout[(size_t)b*2048 + j] = s;  // [b][spin][i][j]
    }
}

// ------------- one doubling level: out[b][q] = in[b][q>>1] @ M[b][q&1] ------
template<bool IN_BF, int OUT_MODE>
__global__ __launch_bounds__(256) void chain_kernel(
    const void* __restrict__ inv, const float* __restrict__ Mb,
    void* __restrict__ outv, int nq_in)
{
    int b = blockIdx.y;
    int q0 = blockIdx.x * 4;
    int nq_out = nq_in * 2;
    __shared__ float parT[2][32][36];   // parent, transposed
    __shared__ float mm[2][32][36];     // site matrices, plain
    __shared__ unsigned short stage[4][1024];  // OUT_MODE 2 staging (8KB)
    int t = threadIdx.x;
    int w = t >> 6, l = t & 63;
    if (w < 2) {
        size_t base = ((size_t)b*nq_in + (q0>>1) + w) * 1024;
#pragma unroll
        for (int r = 0; r < 4; ++r) {
            int e = r*256 + l*4;
            int row = e >> 5, c0 = e & 31;
            float v0, v1, v2, v3;
            if (IN_BF) {
                ushort4 v = *(const ushort4*)((const unsigned short*)inv + base + e);
                v0 = bf2f(v.x); v1 = bf2f(v.y); v2 = bf2f(v.z); v3 = bf2f(v.w);
            } else {
                float4 v = *(const float4*)((const float*)inv + base + e);
                v0 = v.x; v1 = v.y; v2 = v.z; v3 = v.w;
            }
            parT[w][c0+0][row] = v0; parT[w][c0+1][row] = v1;
            parT[w][c0+2][row] = v2; parT[w][c0+3][row] = v3;
        }
    } else {
        const float* src = Mb + ((size_t)b*2 + (w-2)) * 1024;
#pragma unroll
        for (int r = 0; r < 4; ++r) {
            int e = r*256 + l*4;
            float4 v = *(const float4*)(src + e);
            *(float4*)&mm[w-2][e>>5][e&31] = v;
        }
    }
    __syncthreads();
    int q = q0 + w;
    int p = w >> 1, m = w & 1;
    int r0 = (l >> 3) << 2, c0 = (l & 7) << 2;
    float acc[4][4] = {};
#pragma unroll 8
    for (int kk = 0; kk < 32; ++kk) {
        float a[4], bb[4];
        *(float4*)a  = *(const float4*)&parT[p][kk][r0];
        *(float4*)bb = *(const float4*)&mm[m][kk][c0];
#pragma unroll
        for (int i = 0; i < 4; ++i)
#pragma unroll
            for (int j = 0; j < 4; ++j)
                acc[i][j] += a[i]*bb[j];
    }
    size_t ob = ((size_t)b*nq_out + q) * 1024;
    if (OUT_MODE == 0) {
        float* dst = (float*)outv;
#pragma unroll
        for (int i = 0; i < 4; ++i) {
            float4 v = make_float4(acc[i][0], acc[i][1], acc[i][2], acc[i][3]);
            *(float4*)(dst + ob + (r0+i)*32 + c0) = v;
        }
    } else if (OUT_MODE == 1) {
        unsigned short* dst = (unsigned short*)outv;
#pragma unroll
        for (int i = 0; i < 4; ++i) {
            ushort4 v; v.x = f2bf(acc[i][0]); v.y = f2bf(acc[i][1]);
            v.z = f2bf(acc[i][2]); v.w = f2bf(acc[i][3]);
            *(ushort4*)(dst + ob + (r0+i)*32 + c0) = v;
        }
    } else {
        // scatter into XOR-pair layout in LDS, then vectorized copy out
#pragma unroll
        for (int i = 0; i < 4; ++i)
#pragma unroll
            for (int j = 0; j < 4; ++j) {
                int r = r0 + i, c = c0 + j;
                stage[w][((r ^ c) << 5) | c] = f2bf(acc[i][j]);
            }
        __syncthreads();
        unsigned short* dst = (unsigned short*)outv + ((size_t)b*256 + q0) * 1024;
        const uint4* s4 = (const uint4*)&stage[0][0];   // 512 x 16B
        uint4* d4 = (uint4*)dst;
        d4[t] = s4[t];
        d4[t + 256] = s4[t + 256];
    }
}

// ---- pairing via bf16 MFMA: C_b[s][t] = Tr(L_s L_t), LL in XOR-pair layout.
// A[s][k] = LL[s][k] ascending. B[t][k] = LL[t][(k&~31)|((k&31)^d)], d=k>>5.
// Per K-step (BK=32, d fixed): B global loads use 8-block-base XOR (d&24) in
// the address; the within-8 scramble (e=d&7) is fixed in-register before the
// ds_write, so LDS holds true ascending tiles -> plain m97-style NT MFMA loop.
__global__ __launch_bounds__(256) void pair_gemm_mfma(
    const unsigned short* __restrict__ LL,
    float* __restrict__ out, float* __restrict__ norm2)
{
    int b = blockIdx.y;
    int ti = blockIdx.x >> 1, tj = blockIdx.x & 1;
    const unsigned short* Ab = LL + (size_t)b*262144 + (size_t)ti*131072;
    const unsigned short* Bb = LL + (size_t)b*262144 + (size_t)tj*131072;
    __shared__ __align__(16) unsigned short As[2][128][40];  // +8 pad: bank-spread
    __shared__ __align__(16) unsigned short Bs[2][128][40];
    __shared__ float wsum[4];
    int t = threadIdx.x;
    int w = t >> 6, l = t & 63;
    int row0 = t >> 2;          // 0..63 ; second chunk = +64
    int j8 = (t & 3) * 8;       // ushort offset within the 32-block
    int wm = (w >> 1) * 64, wn = (w & 1) * 64;
    int lr = l & 15, lg = l >> 4;

    const unsigned short* Ar0 = Ab + (size_t)row0*1024;
    const unsigned short* Ar1 = Ab + (size_t)(row0+64)*1024;
    const unsigned short* Br0 = Bb + (size_t)row0*1024;
    const unsigned short* Br1 = Bb + (size_t)(row0+64)*1024;

    f32x4 acc[4][4] = {};
    sh8 ra0, ra1, rb0, rb1;

    // prologue: step d=0 (g=0, e=0: no address XOR, no descramble)
    ra0 = *(const sh8*)(Ar0 + j8);
    ra1 = *(const sh8*)(Ar1 + j8);
    rb0 = *(const sh8*)(Br0 + j8);
    rb1 = *(const sh8*)(Br1 + j8);
    *(sh8*)&As[0][row0][j8]    = ra0;
    *(sh8*)&As[0][row0+64][j8] = ra1;
    *(sh8*)&Bs[0][row0][j8]    = rb0;
    *(sh8*)&Bs[0][row0+64][j8] = rb1;
    __syncthreads();

#pragma unroll
    for (int d = 0; d < 32; ++d) {
        int cur = d & 1, nxt = cur ^ 1;
        int dn = d + 1;
        if (dn < 32) {  // prefetch next K-step into registers
            int aoff = dn*32 + j8;
            int boff = dn*32 + (j8 ^ ((dn >> 3) << 3));
            ra0 = *(const sh8*)(Ar0 + aoff);
            ra1 = *(const sh8*)(Ar1 + aoff);
            rb0 = *(const sh8*)(Br0 + boff);
            rb1 = *(const sh8*)(Br1 + boff);
        }
        // MFMA on current buffer
        bf8 av[4], bv[4];
#pragma unroll
        for (int m = 0; m < 4; ++m) {
            av[m] = __builtin_bit_cast(bf8, *(const sh8*)&As[cur][wm + m*16 + lr][lg*8]);
            bv[m] = __builtin_bit_cast(bf8, *(const sh8*)&Bs[cur][wn + m*16 + lr][lg*8]);
        }
#pragma unroll
        for (int m = 0; m < 4; ++m)
#pragma unroll
            for (int n = 0; n < 4; ++n)
                acc[m][n] = __builtin_amdgcn_mfma_f32_16x16x32_bf16(av[m], bv[n], acc[m][n], 0, 0, 0);
        if (dn < 32) {  // write prefetched data (descrambled) into other buffer
            int u = dn & 7;
            *(sh8*)&As[nxt][row0][j8]    = ra0;
            *(sh8*)&As[nxt][row0+64][j8] = ra1;
            *(sh8*)&Bs[nxt][row0][j8]    = xshuf(rb0, u);
            *(sh8*)&Bs[nxt][row0+64][j8] = xshuf(rb1, u);
        }
        __syncthreads();
    }

    // epilogue: write C (f32) + accumulate sum of squares
    float ss = 0.f;
    size_t ob = (size_t)b*65536;
#pragma unroll
    for (int m = 0; m < 4; ++m) {
#pragma unroll
        for (int n = 0; n < 4; ++n) {
            f32x4 v = acc[m][n];
            int s0 = ti*128 + wm + m*16 + lg*4;
            int t0 = tj*128 + wn + n*16 + lr;
            float* op = out + ob + (size_t)s0*256 + t0;
#pragma unroll
            for (int r = 0; r < 4; ++r) {
                op[r*256] = v[r];
                ss += v[r]*v[r];
            }
        }
    }
#pragma unroll
    for (int o = 1; o < 64; o <<= 1) ss += __shfl_xor(ss, o);
    if (l == 0) wsum[w] = ss;
    __syncthreads();
    if (t == 0) atomicAdd(norm2 + b, wsum[0]+wsum[1]+wsum[2]+wsum[3]);
}

// ---------------- normalize rows ----------------
__global__ __launch_bounds__(256) void scale_kernel(
    float* __restrict__ out, const float* __restrict__ norm2)
{
    size_t i = (size_t)blockIdx.x * 256 + threadIdx.x;  // float4 index
    int b = (int)(i >> 14);                              // 16384 float4 / row
    float s = rsqrtf(norm2[b]);
    float4 v = ((const float4*)out)[i];
    v.x *= s; v.y *= s; v.z *= s; v.w *= s;
    ((float4*)out)[i] = v;
}

extern "C" void kernel_launch(void* const* d_in, const int* in_sizes, int n_in,
                              void* d_out, int out_size, void* d_ws, size_t ws_size,
                              hipStream_t stream)
{
    (void)in_sizes; (void)n_in;
    const float* x  = (const float*)d_in[0];
    const float* W1 = (const float*)d_in[1];
    const float* b1 = (const float*)d_in[2];
    const float* W2 = (const float*)d_in[3];
    const float* b2 = (const float*)d_in[4];
    const float* W3 = (const float*)d_in[5];
    const float* b3 = (const float*)d_in[6];
    float* out = (float*)d_out;

    // ---- byte-offset workspace packing (liveness-based, peak ~117 MB) ----
    char* W = (char*)d_ws;
    const size_t MB = 1024*1024;
    unsigned short* LL = (unsigned short*)(W + 0);        // bf16 [128][256][1024]
    unsigned short* X6 = (unsigned short*)(W + 64*MB);    // bf16 [128][128][1024]
    float* X5 = (float*)(W + 0);
    float* X4 = (float*)(W + 96*MB);
    float* X3 = (float*)(W + 32*MB);
    float* X2 = (float*)(W + 112*MB);
    float* X1 = (float*)(W + 40*MB);
    float* Mb = (float*)(W + 116*MB);
    float* nrm = (float*)(W + 117*MB);
    const size_t NEED = 117*MB + 512;
    if (ws_size < NEED) {
        hipMemsetAsync(d_out, 0, (size_t)out_size * sizeof(float), stream);
        return;
    }

    hipMemsetAsync(nrm, 0, BDIM*sizeof(float), stream);
    mlp_kernel<<<BDIM, 256, 0, stream>>>(x, W1, b1, W2, b2, W3, b3, Mb);
    chain_kernel<false,0><<<dim3( 1, BDIM), 256, 0, stream>>>(Mb, Mb, X1,   2);
    chain_kernel<false,0><<<dim3( 2, BDIM), 256, 0, stream>>>(X1, Mb, X2,   4);
    chain_kernel<false,0><<<dim3( 4, BDIM), 256, 0, stream>>>(X2, Mb, X3,   8);
    chain_kernel<false,0><<<dim3( 8, BDIM), 256, 0, stream>>>(X3, Mb, X4,  16);
    chain_kernel<false,0><<<dim3(16, BDIM), 256, 0, stream>>>(X4, Mb, X5,  32);
    chain_kernel<false,1><<<dim3(32, BDIM), 256, 0, stream>>>(X5, Mb, X6,  64);
    chain_kernel<true, 2><<<dim3(64, BDIM), 256, 0, stream>>>(X6, Mb, LL, 128);
    pair_gemm_mfma<<<dim3(4, BDIM), 256, 0, stream>>>(LL, out, nrm);
    scale_kernel<<<8192, 256, 0, stream>>>(out, nrm);
}

// Round 7
// 183.543 us; speedup vs baseline: 2.3989x; 1.2335x over previous
//
#include <hip/hip_runtime.h>
#include <hip/hip_bf16.h>
#include <math.h>

#define BDIM 128   // batch

typedef short sh8 __attribute__((ext_vector_type(8)));
typedef __bf16 bf8 __attribute__((ext_vector_type(8)));
typedef float f32x4 __attribute__((ext_vector_type(4)));

__device__ inline float bf2f(unsigned short u) {
    union { unsigned int i; float f; } v; v.i = ((unsigned int)u) << 16; return v.f;
}
__device__ inline unsigned short f2bf(float f) {
    union { unsigned int i; float f; } v; v.f = f;
    unsigned int x = v.i;
    return (unsigned short)((x + 0x7FFFu + ((x >> 16) & 1u)) >> 16);  // RNE
}

// within-8 ushort XOR shuffle (compile-time folded inside unrolled loops)
__device__ inline sh8 xshuf(sh8 v, int u) {
    switch (u & 7) {
    case 0: return v;
    case 1: return __builtin_shufflevector(v,v,1,0,3,2,5,4,7,6);
    case 2: return __builtin_shufflevector(v,v,2,3,0,1,6,7,4,5);
    case 3: return __builtin_shufflevector(v,v,3,2,1,0,7,6,5,4);
    case 4: return __builtin_shufflevector(v,v,4,5,6,7,0,1,2,3);
    case 5: return __builtin_shufflevector(v,v,5,4,7,6,1,0,3,2);
    case 6: return __builtin_shufflevector(v,v,6,7,4,5,2,3,0,1);
    default: return __builtin_shufflevector(v,v,7,6,5,4,3,2,1,0);
    }
}

// ---------------- MLP encoder: x[128,4] -> M[128,2,32,32] ----
__global__ __launch_bounds__(256) void mlp_kernel(
    const float* __restrict__ x,
    const float* __restrict__ W1, const float* __restrict__ b1,
    const float* __restrict__ W2, const float* __restrict__ b2,
    const float* __restrict__ W3, const float* __restrict__ b3,
    float* __restrict__ Mout)
{
    __shared__ float h1[1024];
    __shared__ float part[8][33];
    __shared__ float h2[32];
    int b = blockIdx.x, t = threadIdx.x;
    float x0 = x[b*4+0], x1 = x[b*4+1], x2 = x[b*4+2], x3 = x[b*4+3];
#pragma unroll
    for (int q = 0; q < 4; ++q) {
        int j = t + 256*q;
        float4 w = *(const float4*)(W1 + (size_t)j*4);
        float v = x0*w.x + x1*w.y + x2*w.z + x3*w.w + b1[j];
        h1[j] = v > 0.f ? v : 0.f;
    }
    __syncthreads();
    {
        int o = t & 31, chunk = t >> 5;
        const float* w2r = W2 + (size_t)o*1024 + chunk*128;
        const float* h1r = h1 + chunk*128;
        float s = 0.f;
#pragma unroll
        for (int k = 0; k < 128; k += 4) {
            float4 w = *(const float4*)(w2r + k);
            s += h1r[k]*w.x + h1r[k+1]*w.y + h1r[k+2]*w.z + h1r[k+3]*w.w;
        }
        part[chunk][o] = s;
    }
    __syncthreads();
    if (t < 32) {
        float s = b2[t];
#pragma unroll
        for (int c = 0; c < 8; ++c) s += part[c][t];
        h2[t] = s > 0.f ? s : 0.f;
    }
    __syncthreads();
#pragma unroll
    for (int q = 0; q < 8; ++q) {
        int j = t + 256*q;
        const float* w3r = W3 + (size_t)j*32;
        float s = b3[j];
#pragma unroll
        for (int i = 0; i < 32; i += 4) {
            float4 w = *(const float4*)(w3r + i);
            s += h2[i]*w.x + h2[i+1]*w.y + h2[i+2]*w.z + h2[i+3]*w.w;
        }
        Mout[(size_t)b*2048 + j] = s;  // [b][spin][i][j]
    }
}

// ---- P2 (4 mats) and P4 (16 mats) per batch, fully in LDS; write P4 fp32 ---
// P2[v] = A[v>>1] @ A[v&1] ; P4[u] = P2[u>>2] @ P2[u&3]. One block per b.
__global__ __launch_bounds__(256) void small_chain(
    const float* __restrict__ Mb, float* __restrict__ P4n)
{
    int b = blockIdx.x, t = threadIdx.x;
    __shared__ float aT[2][32][36], an[2][32][36];    // A transposed / plain
    __shared__ float p2T[4][32][36], p2n[4][32][36];  // P2 transposed / plain
    int w = t >> 6, l = t & 63;
    {
        const float* src = Mb + (size_t)b*2048;
#pragma unroll
        for (int r = 0; r < 2; ++r) {
            int e = t*4 + r*1024;
            float4 v = *(const float4*)(src + e);
            int mat = e >> 10, off = e & 1023;
            int row = off >> 5, c = off & 31;
            *(float4*)&an[mat][row][c] = v;
            aT[mat][c+0][row] = v.x; aT[mat][c+1][row] = v.y;
            aT[mat][c+2][row] = v.z; aT[mat][c+3][row] = v.w;
        }
    }
    __syncthreads();
    int r0 = (l >> 3) << 2, c0 = (l & 7) << 2;
    {   // P2[w]
        float acc[4][4] = {};
#pragma unroll 8
        for (int kk = 0; kk < 32; ++kk) {
            float a[4], bb[4];
            *(float4*)a  = *(const float4*)&aT[w>>1][kk][r0];
            *(float4*)bb = *(const float4*)&an[w&1][kk][c0];
#pragma unroll
            for (int i = 0; i < 4; ++i)
#pragma unroll
                for (int j = 0; j < 4; ++j)
                    acc[i][j] += a[i]*bb[j];
        }
#pragma unroll
        for (int i = 0; i < 4; ++i)
#pragma unroll
            for (int j = 0; j < 4; ++j) {
                p2n[w][r0+i][c0+j] = acc[i][j];
                p2T[w][c0+j][r0+i] = acc[i][j];
            }
    }
    __syncthreads();
#pragma unroll
    for (int it = 0; it < 4; ++it) {   // P4[u], u = (w<<2)|it
        int u = (w << 2) | it;
        float acc[4][4] = {};
#pragma unroll 8
        for (int kk = 0; kk < 32; ++kk) {
            float a[4], bb[4];
            *(float4*)a  = *(const float4*)&p2T[w][kk][r0];   // u>>2 == w
            *(float4*)bb = *(const float4*)&p2n[it][kk][c0];  // u&3 == it
#pragma unroll
            for (int i = 0; i < 4; ++i)
#pragma unroll
                for (int j = 0; j < 4; ++j)
                    acc[i][j] += a[i]*bb[j];
        }
        float* dst = P4n + ((size_t)b*16 + u)*1024;
#pragma unroll
        for (int i = 0; i < 4; ++i)
            *(float4*)(dst + (r0+i)*32 + c0) =
                make_float4(acc[i][0], acc[i][1], acc[i][2], acc[i][3]);
    }
}

// ---- LL[q] = P4[q>>4] @ P4[q&15], written bf16 in XOR-pair layout ----------
// LL[q][((i^j)<<5)|j] = L_q[i][j]. Block: 4 consecutive q (same hi), 4 waves.
__global__ __launch_bounds__(256) void ll_kernel(
    const float* __restrict__ P4n, unsigned short* __restrict__ LL)
{
    int b = blockIdx.y;
    int q0 = blockIdx.x * 4;
    int hi = q0 >> 4;
    __shared__ float parT[32][36];       // P4[hi] transposed
    __shared__ float mm[4][32][36];      // P4[lo_w] plain
    __shared__ unsigned short stage[4][1024];
    int t = threadIdx.x, w = t >> 6, l = t & 63;
    {   // stage hi transposed (whole block)
        const float* src = P4n + ((size_t)b*16 + hi)*1024;
        int e = t*4;
        float4 v = *(const float4*)(src + e);
        int row = e >> 5, c = e & 31;
        parT[c+0][row] = v.x; parT[c+1][row] = v.y;
        parT[c+2][row] = v.z; parT[c+3][row] = v.w;
    }
    {   // stage lo plain (per wave)
        const float* src = P4n + ((size_t)b*16 + ((q0 & 15) | w))*1024;
#pragma unroll
        for (int r = 0; r < 4; ++r) {
            int e = r*256 + l*4;
            *(float4*)&mm[w][e>>5][e&31] = *(const float4*)(src + e);
        }
    }
    __syncthreads();
    int r0 = (l >> 3) << 2, c0 = (l & 7) << 2;
    float acc[4][4] = {};
#pragma unroll 8
    for (int kk = 0; kk < 32; ++kk) {
        float a[4], bb[4];
        *(float4*)a  = *(const float4*)&parT[kk][r0];
        *(float4*)bb = *(const float4*)&mm[w][kk][c0];
#pragma unroll
        for (int i = 0; i < 4; ++i)
#pragma unroll
            for (int j = 0; j < 4; ++j)
                acc[i][j] += a[i]*bb[j];
    }
#pragma unroll
    for (int i = 0; i < 4; ++i)
#pragma unroll
        for (int j = 0; j < 4; ++j) {
            int r = r0 + i, c = c0 + j;
            stage[w][((r ^ c) << 5) | c] = f2bf(acc[i][j]);
        }
    __syncthreads();
    unsigned short* dst = LL + ((size_t)b*256 + q0)*1024;
    const uint4* s4 = (const uint4*)&stage[0][0];
    uint4* d4 = (uint4*)dst;
    d4[t] = s4[t];
    d4[t + 256] = s4[t + 256];
}

// ---- pairing via bf16 MFMA: C_b[s][t] = Tr(L_s L_t), LL in XOR-pair layout.
__global__ __launch_bounds__(256) void pair_gemm_mfma(
    const unsigned short* __restrict__ LL,
    float* __restrict__ out, float* __restrict__ norm2)
{
    int b = blockIdx.y;
    int ti = blockIdx.x >> 1, tj = blockIdx.x & 1;
    const unsigned short* Ab = LL + (size_t)b*262144 + (size_t)ti*131072;
    const unsigned short* Bb = LL + (size_t)b*262144 + (size_t)tj*131072;
    __shared__ __align__(16) unsigned short As[2][128][40];
    __shared__ __align__(16) unsigned short Bs[2][128][40];
    __shared__ float wsum[4];
    int t = threadIdx.x;
    int w = t >> 6, l = t & 63;
    int row0 = t >> 2;
    int j8 = (t & 3) * 8;
    int wm = (w >> 1) * 64, wn = (w & 1) * 64;
    int lr = l & 15, lg = l >> 4;

    const unsigned short* Ar0 = Ab + (size_t)row0*1024;
    const unsigned short* Ar1 = Ab + (size_t)(row0+64)*1024;
    const unsigned short* Br0 = Bb + (size_t)row0*1024;
    const unsigned short* Br1 = Bb + (size_t)(row0+64)*1024;

    f32x4 acc[4][4] = {};
    sh8 ra0, ra1, rb0, rb1;

    ra0 = *(const sh8*)(Ar0 + j8);
    ra1 = *(const sh8*)(Ar1 + j8);
    rb0 = *(const sh8*)(Br0 + j8);
    rb1 = *(const sh8*)(Br1 + j8);
    *(sh8*)&As[0][row0][j8]    = ra0;
    *(sh8*)&As[0][row0+64][j8] = ra1;
    *(sh8*)&Bs[0][row0][j8]    = rb0;
    *(sh8*)&Bs[0][row0+64][j8] = rb1;
    __syncthreads();

#pragma unroll
    for (int d = 0; d < 32; ++d) {
        int cur = d & 1, nxt = cur ^ 1;
        int dn = d + 1;
        if (dn < 32) {
            int aoff = dn*32 + j8;
            int boff = dn*32 + (j8 ^ ((dn >> 3) << 3));
            ra0 = *(const sh8*)(Ar0 + aoff);
            ra1 = *(const sh8*)(Ar1 + aoff);
            rb0 = *(const sh8*)(Br0 + boff);
            rb1 = *(const sh8*)(Br1 + boff);
        }
        bf8 av[4], bv[4];
#pragma unroll
        for (int m = 0; m < 4; ++m) {
            av[m] = __builtin_bit_cast(bf8, *(const sh8*)&As[cur][wm + m*16 + lr][lg*8]);
            bv[m] = __builtin_bit_cast(bf8, *(const sh8*)&Bs[cur][wn + m*16 + lr][lg*8]);
        }
#pragma unroll
        for (int m = 0; m < 4; ++m)
#pragma unroll
            for (int n = 0; n < 4; ++n)
                acc[m][n] = __builtin_amdgcn_mfma_f32_16x16x32_bf16(av[m], bv[n], acc[m][n], 0, 0, 0);
        if (dn < 32) {
            int u = dn & 7;
            *(sh8*)&As[nxt][row0][j8]    = ra0;
            *(sh8*)&As[nxt][row0+64][j8] = ra1;
            *(sh8*)&Bs[nxt][row0][j8]    = xshuf(rb0, u);
            *(sh8*)&Bs[nxt][row0+64][j8] = xshuf(rb1, u);
        }
        __syncthreads();
    }

    float ss = 0.f;
    size_t ob = (size_t)b*65536;
#pragma unroll
    for (int m = 0; m < 4; ++m) {
#pragma unroll
        for (int n = 0; n < 4; ++n) {
            f32x4 v = acc[m][n];
            int s0 = ti*128 + wm + m*16 + lg*4;
            int t0 = tj*128 + wn + n*16 + lr;
            float* op = out + ob + (size_t)s0*256 + t0;
#pragma unroll
            for (int r = 0; r < 4; ++r) {
                op[r*256] = v[r];
                ss += v[r]*v[r];
            }
        }
    }
#pragma unroll
    for (int o = 1; o < 64; o <<= 1) ss += __shfl_xor(ss, o);
    if (l == 0) wsum[w] = ss;
    __syncthreads();
    if (t == 0) atomicAdd(norm2 + b, wsum[0]+wsum[1]+wsum[2]+wsum[3]);
}

// ---------------- normalize rows ----------------
__global__ __launch_bounds__(256) void scale_kernel(
    float* __restrict__ out, const float* __restrict__ norm2)
{
    size_t i = (size_t)blockIdx.x * 256 + threadIdx.x;  // float4 index
    int b = (int)(i >> 14);
    float s = rsqrtf(norm2[b]);
    float4 v = ((const float4*)out)[i];
    v.x *= s; v.y *= s; v.z *= s; v.w *= s;
    ((float4*)out)[i] = v;
}

extern "C" void kernel_launch(void* const* d_in, const int* in_sizes, int n_in,
                              void* d_out, int out_size, void* d_ws, size_t ws_size,
                              hipStream_t stream)
{
    (void)in_sizes; (void)n_in;
    const float* x  = (const float*)d_in[0];
    const float* W1 = (const float*)d_in[1];
    const float* b1 = (const float*)d_in[2];
    const float* W2 = (const float*)d_in[3];
    const float* b2 = (const float*)d_in[4];
    const float* W3 = (const float*)d_in[5];
    const float* b3 = (const float*)d_in[6];
    float* out = (float*)d_out;

    // ---- workspace (peak 73 MB + 512 B) ----
    char* W = (char*)d_ws;
    const size_t MB = 1024*1024;
    unsigned short* LL = (unsigned short*)(W + 0);       // bf16 [128][256][1024] 64MB
    float* P4 = (float*)(W + 64*MB);                     // f32 [128][16][1024]    8MB
    float* Mb = (float*)(W + 72*MB);                     // f32 [128][2][1024]     1MB
    float* nrm = (float*)(W + 73*MB);                    // f32 [128]
    const size_t NEED = 73*MB + 512;
    if (ws_size < NEED) {
        hipMemsetAsync(d_out, 0, (size_t)out_size * sizeof(float), stream);
        return;
    }

    hipMemsetAsync(nrm, 0, BDIM*sizeof(float), stream);
    mlp_kernel<<<BDIM, 256, 0, stream>>>(x, W1, b1, W2, b2, W3, b3, Mb);
    small_chain<<<BDIM, 256, 0, stream>>>(Mb, P4);
    ll_kernel<<<dim3(64, BDIM), 256, 0, stream>>>(P4, LL);
    pair_gemm_mfma<<<dim3(4, BDIM), 256, 0, stream>>>(LL, out, nrm);
    scale_kernel<<<8192, 256, 0, stream>>>(out, nrm);
}

// Round 10
// 161.185 us; speedup vs baseline: 2.7316x; 1.1387x over previous
//
#include <hip/hip_runtime.h>
#include <hip/hip_bf16.h>
#include <math.h>

#define BDIM 128   // batch

typedef short sh8 __attribute__((ext_vector_type(8)));
typedef __bf16 bf8 __attribute__((ext_vector_type(8)));
typedef float f32x4 __attribute__((ext_vector_type(4)));

__device__ inline float bf2f(unsigned short u) {
    union { unsigned int i; float f; } v; v.i = ((unsigned int)u) << 16; return v.f;
}
__device__ inline unsigned short f2bf(float f) {
    union { unsigned int i; float f; } v; v.f = f;
    unsigned int x = v.i;
    return (unsigned short)((x + 0x7FFFu + ((x >> 16) & 1u)) >> 16);  // RNE
}

// within-8 ushort XOR shuffle (compile-time folded inside unrolled loops)
__device__ inline sh8 xshuf(sh8 v, int u) {
    switch (u & 7) {
    case 0: return v;
    case 1: return __builtin_shufflevector(v,v,1,0,3,2,5,4,7,6);
    case 2: return __builtin_shufflevector(v,v,2,3,0,1,6,7,4,5);
    case 3: return __builtin_shufflevector(v,v,3,2,1,0,7,6,5,4);
    case 4: return __builtin_shufflevector(v,v,4,5,6,7,0,1,2,3);
    case 5: return __builtin_shufflevector(v,v,5,4,7,6,1,0,3,2);
    case 6: return __builtin_shufflevector(v,v,6,7,4,5,2,3,0,1);
    default: return __builtin_shufflevector(v,v,7,6,5,4,3,2,1,0);
    }
}

// ---- fused encoder: MLP -> A (LDS only) -> P2 -> P4 (bf16, plain+transposed)
// One block per batch b. Also zero-inits norm2[b].
__global__ __launch_bounds__(256) void enc_fused(
    const float* __restrict__ x,
    const float* __restrict__ W1, const float* __restrict__ b1,
    const float* __restrict__ W2, const float* __restrict__ b2,
    const float* __restrict__ W3, const float* __restrict__ b3,
    unsigned short* __restrict__ P4n, unsigned short* __restrict__ P4t,
    float* __restrict__ nrm)
{
    __shared__ float h1[1024];
    __shared__ float part[8][33];
    __shared__ float h2[32];
    __shared__ float aT[2][32][36], an[2][32][36];
    __shared__ float p2T[4][32][36], p2n[4][32][36];
    int b = blockIdx.x, t = threadIdx.x;
    if (t == 0) nrm[b] = 0.f;
    float x0 = x[b*4+0], x1 = x[b*4+1], x2 = x[b*4+2], x3 = x[b*4+3];
#pragma unroll
    for (int q = 0; q < 4; ++q) {
        int j = t + 256*q;
        float4 w = *(const float4*)(W1 + (size_t)j*4);
        float v = x0*w.x + x1*w.y + x2*w.z + x3*w.w + b1[j];
        h1[j] = v > 0.f ? v : 0.f;
    }
    __syncthreads();
    {
        int o = t & 31, chunk = t >> 5;
        const float* w2r = W2 + (size_t)o*1024 + chunk*128;
        const float* h1r = h1 + chunk*128;
        float s = 0.f;
#pragma unroll
        for (int k = 0; k < 128; k += 4) {
            float4 w = *(const float4*)(w2r + k);
            s += h1r[k]*w.x + h1r[k+1]*w.y + h1r[k+2]*w.z + h1r[k+3]*w.w;
        }
        part[chunk][o] = s;
    }
    __syncthreads();
    if (t < 32) {
        float s = b2[t];
#pragma unroll
        for (int c = 0; c < 8; ++c) s += part[c][t];
        h2[t] = s > 0.f ? s : 0.f;
    }
    __syncthreads();
#pragma unroll
    for (int q = 0; q < 8; ++q) {   // e = W3 h2 + b3 -> A matrices in LDS
        int j = t + 256*q;
        const float* w3r = W3 + (size_t)j*32;
        float s = b3[j];
#pragma unroll
        for (int i = 0; i < 32; i += 4) {
            float4 w = *(const float4*)(w3r + i);
            s += h2[i]*w.x + h2[i+1]*w.y + h2[i+2]*w.z + h2[i+3]*w.w;
        }
        int spin = j >> 10, off = j & 1023;
        int row = off >> 5, c = off & 31;
        an[spin][row][c] = s;
        aT[spin][c][row] = s;
    }
    __syncthreads();
    int w = t >> 6, l = t & 63;
    int r0 = (l >> 3) << 2, c0 = (l & 7) << 2;
    {   // P2[w] = A[w>>1] @ A[w&1]
        float acc[4][4] = {};
#pragma unroll 8
        for (int kk = 0; kk < 32; ++kk) {
            float a[4], bb[4];
            *(float4*)a  = *(const float4*)&aT[w>>1][kk][r0];
            *(float4*)bb = *(const float4*)&an[w&1][kk][c0];
#pragma unroll
            for (int i = 0; i < 4; ++i)
#pragma unroll
                for (int j = 0; j < 4; ++j)
                    acc[i][j] += a[i]*bb[j];
        }
#pragma unroll
        for (int i = 0; i < 4; ++i)
#pragma unroll
            for (int j = 0; j < 4; ++j) {
                p2n[w][r0+i][c0+j] = acc[i][j];
                p2T[w][c0+j][r0+i] = acc[i][j];
            }
    }
    __syncthreads();
#pragma unroll
    for (int it = 0; it < 4; ++it) {   // P4[u] = P2[w] @ P2[it], u=(w<<2)|it
        int u = (w << 2) | it;
        float acc[4][4] = {};
#pragma unroll 8
        for (int kk = 0; kk < 32; ++kk) {
            float a[4], bb[4];
            *(float4*)a  = *(const float4*)&p2T[w][kk][r0];
            *(float4*)bb = *(const float4*)&p2n[it][kk][c0];
#pragma unroll
            for (int i = 0; i < 4; ++i)
#pragma unroll
                for (int j = 0; j < 4; ++j)
                    acc[i][j] += a[i]*bb[j];
        }
        unsigned short* dstN = P4n + ((size_t)b*16 + u)*1024;
        unsigned short* dstT = P4t + ((size_t)b*16 + u)*1024;
#pragma unroll
        for (int i = 0; i < 4; ++i) {
            ushort4 v; v.x = f2bf(acc[i][0]); v.y = f2bf(acc[i][1]);
            v.z = f2bf(acc[i][2]); v.w = f2bf(acc[i][3]);
            *(ushort4*)(dstN + (r0+i)*32 + c0) = v;
        }
#pragma unroll
        for (int j = 0; j < 4; ++j) {
            ushort4 v; v.x = f2bf(acc[0][j]); v.y = f2bf(acc[1][j]);
            v.z = f2bf(acc[2][j]); v.w = f2bf(acc[3][j]);
            *(ushort4*)(dstT + (c0+j)*32 + r0) = v;
        }
    }
}

// ---- LL via MFMA: per (b,hi) C(32x512) = P4[hi] @ [P4[0..15]], K=32 -------
// A[i][k]=P4n[hi][i*32+k]; B[col][k]=P4t[col>>5][(col&31)*32+k]  (NT GEMM).
// Output scattered to XOR-pair layout: LL[q][((i^j)<<5)|j], q=hi*16+(col>>5).
__global__ __launch_bounds__(256) void ll_mfma(
    const unsigned short* __restrict__ P4n, const unsigned short* __restrict__ P4t,
    unsigned short* __restrict__ LL)
{
    int hi = blockIdx.x, b = blockIdx.y;
    __shared__ __align__(16) unsigned short As[32][40];
    __shared__ __align__(16) unsigned short Bs[512][40];
    __shared__ __align__(16) unsigned short outst[16][1024];  // 32 KB
    int t = threadIdx.x;
    int w = t >> 6, l = t & 63;
    int lr = l & 15, lg = l >> 4;
    int wn = w * 128;

    {   // stage A (first 128 threads): 32 rows x 4 sh8
        if (t < 128) {
            int i = t >> 2, k8 = (t & 3) * 8;
            *(sh8*)&As[i][k8] = *(const sh8*)(P4n + ((size_t)b*16 + hi)*1024 + i*32 + k8);
        }
        // stage B: 512 rows x 4 sh8 = 2048 sh8
#pragma unroll
        for (int rep = 0; rep < 8; ++rep) {
            int flat = rep*256 + t;
            int n = flat >> 2, k8 = (flat & 3) * 8;
            *(sh8*)&Bs[n][k8] =
                *(const sh8*)(P4t + ((size_t)b*16 + (n >> 5))*1024 + (n & 31)*32 + k8);
        }
    }
    __syncthreads();

    f32x4 acc[2][8] = {};
    bf8 av[2], bv[8];
#pragma unroll
    for (int m = 0; m < 2; ++m)
        av[m] = __builtin_bit_cast(bf8, *(const sh8*)&As[m*16 + lr][lg*8]);
#pragma unroll
    for (int n = 0; n < 8; ++n)
        bv[n] = __builtin_bit_cast(bf8, *(const sh8*)&Bs[wn + n*16 + lr][lg*8]);
#pragma unroll
    for (int m = 0; m < 2; ++m)
#pragma unroll
        for (int n = 0; n < 8; ++n)
            acc[m][n] = __builtin_amdgcn_mfma_f32_16x16x32_bf16(av[m], bv[n], acc[m][n], 0, 0, 0);
    __syncthreads();

    // scatter to XOR-pair layout in LDS
#pragma unroll
    for (int m = 0; m < 2; ++m)
#pragma unroll
        for (int n = 0; n < 8; ++n) {
            f32x4 v = acc[m][n];
            int col = wn + n*16 + lr;
            int qlo = col >> 5, j = col & 31;
#pragma unroll
            for (int r = 0; r < 4; ++r) {
                int i = m*16 + lg*4 + r;
                outst[qlo][((i ^ j) << 5) | j] = f2bf(v[r]);
            }
        }
    __syncthreads();
    unsigned short* dst = LL + ((size_t)b*256 + hi*16)*1024;
    const uint4* s4 = (const uint4*)&outst[0][0];   // 2048 x 16B
    uint4* d4 = (uint4*)dst;
#pragma unroll
    for (int rep = 0; rep < 8; ++rep)
        d4[rep*256 + t] = s4[rep*256 + t];
}

// ---- pairing via bf16 MFMA: C_b[s][t] = Tr(L_s L_t), LL in XOR-pair layout.
__global__ __launch_bounds__(256) void pair_gemm_mfma(
    const unsigned short* __restrict__ LL,
    float* __restrict__ out, float* __restrict__ norm2)
{
    int b = blockIdx.y;
    int ti = blockIdx.x >> 1, tj = blockIdx.x & 1;
    const unsigned short* Ab = LL + (size_t)b*262144 + (size_t)ti*131072;
    const unsigned short* Bb = LL + (size_t)b*262144 + (size_t)tj*131072;
    __shared__ __align__(16) unsigned short As[2][128][40];
    __shared__ __align__(16) unsigned short Bs[2][128][40];
    __shared__ float wsum[4];
    int t = threadIdx.x;
    int w = t >> 6, l = t & 63;
    int row0 = t >> 2;
    int j8 = (t & 3) * 8;
    int wm = (w >> 1) * 64, wn = (w & 1) * 64;
    int lr = l & 15, lg = l >> 4;

    const unsigned short* Ar0 = Ab + (size_t)row0*1024;
    const unsigned short* Ar1 = Ab + (size_t)(row0+64)*1024;
    const unsigned short* Br0 = Bb + (size_t)row0*1024;
    const unsigned short* Br1 = Bb + (size_t)(row0+64)*1024;

    f32x4 acc[4][4] = {};
    sh8 ra0, ra1, rb0, rb1;

    ra0 = *(const sh8*)(Ar0 + j8);
    ra1 = *(const sh8*)(Ar1 + j8);
    rb0 = *(const sh8*)(Br0 + j8);
    rb1 = *(const sh8*)(Br1 + j8);
    *(sh8*)&As[0][row0][j8]    = ra0;
    *(sh8*)&As[0][row0+64][j8] = ra1;
    *(sh8*)&Bs[0][row0][j8]    = rb0;
    *(sh8*)&Bs[0][row0+64][j8] = rb1;
    __syncthreads();

#pragma unroll
    for (int d = 0; d < 32; ++d) {
        int cur = d & 1, nxt = cur ^ 1;
        int dn = d + 1;
        if (dn < 32) {
            int aoff = dn*32 + j8;
            int boff = dn*32 + (j8 ^ ((dn >> 3) << 3));
            ra0 = *(const sh8*)(Ar0 + aoff);
            ra1 = *(const sh8*)(Ar1 + aoff);
            rb0 = *(const sh8*)(Br0 + boff);
            rb1 = *(const sh8*)(Br1 + boff);
        }
        bf8 av[4], bv[4];
#pragma unroll
        for (int m = 0; m < 4; ++m) {
            av[m] = __builtin_bit_cast(bf8, *(const sh8*)&As[cur][wm + m*16 + lr][lg*8]);
            bv[m] = __builtin_bit_cast(bf8, *(const sh8*)&Bs[cur][wn + m*16 + lr][lg*8]);
        }
#pragma unroll
        for (int m = 0; m < 4; ++m)
#pragma unroll
            for (int n = 0; n < 4; ++n)
                acc[m][n] = __builtin_amdgcn_mfma_f32_16x16x32_bf16(av[m], bv[n], acc[m][n], 0, 0, 0);
        if (dn < 32) {
            int u = dn & 7;
            *(sh8*)&As[nxt][row0][j8]    = ra0;
            *(sh8*)&As[nxt][row0+64][j8] = ra1;
            *(sh8*)&Bs[nxt][row0][j8]    = xshuf(rb0, u);
            *(sh8*)&Bs[nxt][row0+64][j8] = xshuf(rb1, u);
        }
        __syncthreads();
    }

    float ss = 0.f;
    size_t ob = (size_t)b*65536;
#pragma unroll
    for (int m = 0; m < 4; ++m) {
#pragma unroll
        for (int n = 0; n < 4; ++n) {
            f32x4 v = acc[m][n];
            int s0 = ti*128 + wm + m*16 + lg*4;
            int t0 = tj*128 + wn + n*16 + lr;
            float* op = out + ob + (size_t)s0*256 + t0;
#pragma unroll
            for (int r = 0; r < 4; ++r) {
                op[r*256] = v[r];
                ss += v[r]*v[r];
            }
        }
    }
#pragma unroll
    for (int o = 1; o < 64; o <<= 1) ss += __shfl_xor(ss, o);
    if (l == 0) wsum[w] = ss;
    __syncthreads();
    if (t == 0) atomicAdd(norm2 + b, wsum[0]+wsum[1]+wsum[2]+wsum[3]);
}

// ---------------- normalize rows ----------------
__global__ __launch_bounds__(256) void scale_kernel(
    float* __restrict__ out, const float* __restrict__ norm2)
{
    size_t i = (size_t)blockIdx.x * 256 + threadIdx.x;  // float4 index
    int b = (int)(i >> 14);
    float s = rsqrtf(norm2[b]);
    float4 v = ((const float4*)out)[i];
    v.x *= s; v.y *= s; v.z *= s; v.w *= s;
    ((float4*)out)[i] = v;
}

extern "C" void kernel_launch(void* const* d_in, const int* in_sizes, int n_in,
                              void* d_out, int out_size, void* d_ws, size_t ws_size,
                              hipStream_t stream)
{
    (void)in_sizes; (void)n_in;
    const float* x  = (const float*)d_in[0];
    const float* W1 = (const float*)d_in[1];
    const float* b1 = (const float*)d_in[2];
    const float* W2 = (const float*)d_in[3];
    const float* b2 = (const float*)d_in[4];
    const float* W3 = (const float*)d_in[5];
    const float* b3 = (const float*)d_in[6];
    float* out = (float*)d_out;

    // ---- workspace (peak 72 MB + 512 B) ----
    char* W = (char*)d_ws;
    const size_t MB = 1024*1024;
    unsigned short* LL  = (unsigned short*)(W + 0);      // bf16 [128][256][1024] 64MB
    unsigned short* P4n = (unsigned short*)(W + 64*MB);  // bf16 [128][16][1024]   4MB
    unsigned short* P4t = (unsigned short*)(W + 68*MB);  // bf16 [128][16][1024]   4MB
    float* nrm = (float*)(W + 72*MB);                    // f32 [128]
    const size_t NEED = 72*MB + 512;
    if (ws_size < NEED) {
        hipMemsetAsync(d_out, 0, (size_t)out_size * sizeof(float), stream);
        return;
    }

    enc_fused<<<BDIM, 256, 0, stream>>>(x, W1, b1, W2, b2, W3, b3, P4n, P4t, nrm);
    ll_mfma<<<dim3(16, BDIM), 256, 0, stream>>>(P4n, P4t, LL);
    pair_gemm_mfma<<<dim3(4, BDIM), 256, 0, stream>>>(LL, out, nrm);
    scale_kernel<<<8192, 256, 0, stream>>>(out, nrm);
}

// Round 15
// 153.715 us; speedup vs baseline: 2.8643x; 1.0486x over previous
//
#include <hip/hip_runtime.h>
#include <hip/hip_bf16.h>
#include <math.h>

#define BDIM 128   // batch

typedef short sh8 __attribute__((ext_vector_type(8)));
typedef __bf16 bf8 __attribute__((ext_vector_type(8)));
typedef float f32x4 __attribute__((ext_vector_type(4)));

__device__ inline float bf2f(unsigned short u) {
    union { unsigned int i; float f; } v; v.i = ((unsigned int)u) << 16; return v.f;
}
__device__ inline unsigned short f2bf(float f) {
    union { unsigned int i; float f; } v; v.f = f;
    unsigned int x = v.i;
    return (unsigned short)((x + 0x7FFFu + ((x >> 16) & 1u)) >> 16);  // RNE
}

// within-8 ushort XOR shuffle (compile-time folded inside unrolled loops)
__device__ inline sh8 xshuf(sh8 v, int u) {
    switch (u & 7) {
    case 0: return v;
    case 1: return __builtin_shufflevector(v,v,1,0,3,2,5,4,7,6);
    case 2: return __builtin_shufflevector(v,v,2,3,0,1,6,7,4,5);
    case 3: return __builtin_shufflevector(v,v,3,2,1,0,7,6,5,4);
    case 4: return __builtin_shufflevector(v,v,4,5,6,7,0,1,2,3);
    case 5: return __builtin_shufflevector(v,v,5,4,7,6,1,0,3,2);
    case 6: return __builtin_shufflevector(v,v,6,7,4,5,2,3,0,1);
    default: return __builtin_shufflevector(v,v,7,6,5,4,3,2,1,0);
    }
}

// ---- fused encoder: MLP -> A (LDS only) -> P2 -> P4 (bf16, plain+transposed)
// One block per batch b. Also zero-inits norm2[b].
__global__ __launch_bounds__(256) void enc_fused(
    const float* __restrict__ x,
    const float* __restrict__ W1, const float* __restrict__ b1,
    const float* __restrict__ W2, const float* __restrict__ b2,
    const float* __restrict__ W3, const float* __restrict__ b3,
    unsigned short* __restrict__ P4n, unsigned short* __restrict__ P4t,
    float* __restrict__ nrm)
{
    __shared__ float h1[1024];
    __shared__ float part[8][33];
    __shared__ float h2[32];
    __shared__ float aT[2][32][36], an[2][32][36];
    __shared__ float p2T[4][32][36], p2n[4][32][36];
    int b = blockIdx.x, t = threadIdx.x;
    if (t == 0) nrm[b] = 0.f;
    float x0 = x[b*4+0], x1 = x[b*4+1], x2 = x[b*4+2], x3 = x[b*4+3];
#pragma unroll
    for (int q = 0; q < 4; ++q) {
        int j = t + 256*q;
        float4 w = *(const float4*)(W1 + (size_t)j*4);
        float v = x0*w.x + x1*w.y + x2*w.z + x3*w.w + b1[j];
        h1[j] = v > 0.f ? v : 0.f;
    }
    __syncthreads();
    {
        int o = t & 31, chunk = t >> 5;
        const float* w2r = W2 + (size_t)o*1024 + chunk*128;
        const float* h1r = h1 + chunk*128;
        float s = 0.f;
#pragma unroll
        for (int k = 0; k < 128; k += 4) {
            float4 w = *(const float4*)(w2r + k);
            s += h1r[k]*w.x + h1r[k+1]*w.y + h1r[k+2]*w.z + h1r[k+3]*w.w;
        }
        part[chunk][o] = s;
    }
    __syncthreads();
    if (t < 32) {
        float s = b2[t];
#pragma unroll
        for (int c = 0; c < 8; ++c) s += part[c][t];
        h2[t] = s > 0.f ? s : 0.f;
    }
    __syncthreads();
#pragma unroll
    for (int q = 0; q < 8; ++q) {   // e = W3 h2 + b3 -> A matrices in LDS
        int j = t + 256*q;
        const float* w3r = W3 + (size_t)j*32;
        float s = b3[j];
#pragma unroll
        for (int i = 0; i < 32; i += 4) {
            float4 w = *(const float4*)(w3r + i);
            s += h2[i]*w.x + h2[i+1]*w.y + h2[i+2]*w.z + h2[i+3]*w.w;
        }
        int spin = j >> 10, off = j & 1023;
        int row = off >> 5, c = off & 31;
        an[spin][row][c] = s;
        aT[spin][c][row] = s;
    }
    __syncthreads();
    int w = t >> 6, l = t & 63;
    int r0 = (l >> 3) << 2, c0 = (l & 7) << 2;
    {   // P2[w] = A[w>>1] @ A[w&1]
        float acc[4][4] = {};
#pragma unroll 8
        for (int kk = 0; kk < 32; ++kk) {
            float a[4], bb[4];
            *(float4*)a  = *(const float4*)&aT[w>>1][kk][r0];
            *(float4*)bb = *(const float4*)&an[w&1][kk][c0];
#pragma unroll
            for (int i = 0; i < 4; ++i)
#pragma unroll
                for (int j = 0; j < 4; ++j)
                    acc[i][j] += a[i]*bb[j];
        }
#pragma unroll
        for (int i = 0; i < 4; ++i)
#pragma unroll
            for (int j = 0; j < 4; ++j) {
                p2n[w][r0+i][c0+j] = acc[i][j];
                p2T[w][c0+j][r0+i] = acc[i][j];
            }
    }
    __syncthreads();
#pragma unroll
    for (int it = 0; it < 4; ++it) {   // P4[u] = P2[w] @ P2[it], u=(w<<2)|it
        int u = (w << 2) | it;
        float acc[4][4] = {};
#pragma unroll 8
        for (int kk = 0; kk < 32; ++kk) {
            float a[4], bb[4];
            *(float4*)a  = *(const float4*)&p2T[w][kk][r0];
            *(float4*)bb = *(const float4*)&p2n[it][kk][c0];
#pragma unroll
            for (int i = 0; i < 4; ++i)
#pragma unroll
                for (int j = 0; j < 4; ++j)
                    acc[i][j] += a[i]*bb[j];
        }
        unsigned short* dstN = P4n + ((size_t)b*16 + u)*1024;
        unsigned short* dstT = P4t + ((size_t)b*16 + u)*1024;
#pragma unroll
        for (int i = 0; i < 4; ++i) {
            ushort4 v; v.x = f2bf(acc[i][0]); v.y = f2bf(acc[i][1]);
            v.z = f2bf(acc[i][2]); v.w = f2bf(acc[i][3]);
            *(ushort4*)(dstN + (r0+i)*32 + c0) = v;
        }
#pragma unroll
        for (int j = 0; j < 4; ++j) {
            ushort4 v; v.x = f2bf(acc[0][j]); v.y = f2bf(acc[1][j]);
            v.z = f2bf(acc[2][j]); v.w = f2bf(acc[3][j]);
            *(ushort4*)(dstT + (c0+j)*32 + r0) = v;
        }
    }
}

// ---- LL via MFMA: per (b,hi) C(32x512) = P4[hi] @ [P4[0..15]], K=32 -------
__global__ __launch_bounds__(256) void ll_mfma(
    const unsigned short* __restrict__ P4n, const unsigned short* __restrict__ P4t,
    unsigned short* __restrict__ LL)
{
    int hi = blockIdx.x, b = blockIdx.y;
    __shared__ __align__(16) unsigned short As[32][40];
    __shared__ __align__(16) unsigned short Bs[512][40];
    __shared__ __align__(16) unsigned short outst[16][1024];  // 32 KB
    int t = threadIdx.x;
    int w = t >> 6, l = t & 63;
    int lr = l & 15, lg = l >> 4;
    int wn = w * 128;

    {   // stage A (first 128 threads): 32 rows x 4 sh8
        if (t < 128) {
            int i = t >> 2, k8 = (t & 3) * 8;
            *(sh8*)&As[i][k8] = *(const sh8*)(P4n + ((size_t)b*16 + hi)*1024 + i*32 + k8);
        }
        // stage B: 512 rows x 4 sh8 = 2048 sh8
#pragma unroll
        for (int rep = 0; rep < 8; ++rep) {
            int flat = rep*256 + t;
            int n = flat >> 2, k8 = (flat & 3) * 8;
            *(sh8*)&Bs[n][k8] =
                *(const sh8*)(P4t + ((size_t)b*16 + (n >> 5))*1024 + (n & 31)*32 + k8);
        }
    }
    __syncthreads();

    f32x4 acc[2][8] = {};
    bf8 av[2], bv[8];
#pragma unroll
    for (int m = 0; m < 2; ++m)
        av[m] = __builtin_bit_cast(bf8, *(const sh8*)&As[m*16 + lr][lg*8]);
#pragma unroll
    for (int n = 0; n < 8; ++n)
        bv[n] = __builtin_bit_cast(bf8, *(const sh8*)&Bs[wn + n*16 + lr][lg*8]);
#pragma unroll
    for (int m = 0; m < 2; ++m)
#pragma unroll
        for (int n = 0; n < 8; ++n)
            acc[m][n] = __builtin_amdgcn_mfma_f32_16x16x32_bf16(av[m], bv[n], acc[m][n], 0, 0, 0);
    __syncthreads();

    // scatter to XOR-pair layout in LDS
#pragma unroll
    for (int m = 0; m < 2; ++m)
#pragma unroll
        for (int n = 0; n < 8; ++n) {
            f32x4 v = acc[m][n];
            int col = wn + n*16 + lr;
            int qlo = col >> 5, j = col & 31;
#pragma unroll
            for (int r = 0; r < 4; ++r) {
                int i = m*16 + lg*4 + r;
                outst[qlo][((i ^ j) << 5) | j] = f2bf(v[r]);
            }
        }
    __syncthreads();
    unsigned short* dst = LL + ((size_t)b*256 + hi*16)*1024;
    const uint4* s4 = (const uint4*)&outst[0][0];   // 2048 x 16B
    uint4* d4 = (uint4*)dst;
#pragma unroll
    for (int rep = 0; rep < 8; ++rep)
        d4[rep*256 + t] = s4[rep*256 + t];
}

// ---- pairing via bf16 MFMA, symmetric: blocks (0,0),(0,1)+mirror,(1,1) ----
// C_b[s][t] = Tr(L_s L_t) = C_b[t][s]; writes unnormalized C + norm2 atomics.
__global__ __launch_bounds__(256) void pair_sym(
    const unsigned short* __restrict__ LL,
    float* __restrict__ out, float* __restrict__ norm2)
{
    int b = blockIdx.y;
    int bx = blockIdx.x;
    int ti = (bx >> 1);            // 0,0,1
    int tj = (bx + 1) >> 1;        // 0,1,1
    const unsigned short* Ab = LL + (size_t)b*262144 + (size_t)ti*131072;
    const unsigned short* Bb = LL + (size_t)b*262144 + (size_t)tj*131072;
    __shared__ __align__(16) unsigned short As[2][128][40];
    __shared__ __align__(16) unsigned short Bs[2][128][40];
    __shared__ float wsum[4];
    int t = threadIdx.x;
    int w = t >> 6, l = t & 63;
    int row0 = t >> 2;
    int j8 = (t & 3) * 8;
    int wm = (w >> 1) * 64, wn = (w & 1) * 64;
    int lr = l & 15, lg = l >> 4;

    const unsigned short* Ar0 = Ab + (size_t)row0*1024;
    const unsigned short* Ar1 = Ab + (size_t)(row0+64)*1024;
    const unsigned short* Br0 = Bb + (size_t)row0*1024;
    const unsigned short* Br1 = Bb + (size_t)(row0+64)*1024;

    f32x4 acc[4][4] = {};
    sh8 ra0, ra1, rb0, rb1;

    ra0 = *(const sh8*)(Ar0 + j8);
    ra1 = *(const sh8*)(Ar1 + j8);
    rb0 = *(const sh8*)(Br0 + j8);
    rb1 = *(const sh8*)(Br1 + j8);
    *(sh8*)&As[0][row0][j8]    = ra0;
    *(sh8*)&As[0][row0+64][j8] = ra1;
    *(sh8*)&Bs[0][row0][j8]    = rb0;
    *(sh8*)&Bs[0][row0+64][j8] = rb1;
    __syncthreads();

#pragma unroll
    for (int d = 0; d < 32; ++d) {
        int cur = d & 1, nxt = cur ^ 1;
        int dn = d + 1;
        if (dn < 32) {
            int aoff = dn*32 + j8;
            int boff = dn*32 + (j8 ^ ((dn >> 3) << 3));
            ra0 = *(const sh8*)(Ar0 + aoff);
            ra1 = *(const sh8*)(Ar1 + aoff);
            rb0 = *(const sh8*)(Br0 + boff);
            rb1 = *(const sh8*)(Br1 + boff);
        }
        bf8 av[4], bv[4];
#pragma unroll
        for (int m = 0; m < 4; ++m) {
            av[m] = __builtin_bit_cast(bf8, *(const sh8*)&As[cur][wm + m*16 + lr][lg*8]);
            bv[m] = __builtin_bit_cast(bf8, *(const sh8*)&Bs[cur][wn + m*16 + lr][lg*8]);
        }
#pragma unroll
        for (int m = 0; m < 4; ++m)
#pragma unroll
            for (int n = 0; n < 4; ++n)
                acc[m][n] = __builtin_amdgcn_mfma_f32_16x16x32_bf16(av[m], bv[n], acc[m][n], 0, 0, 0);
        if (dn < 32) {
            int u = dn & 7;
            *(sh8*)&As[nxt][row0][j8]    = ra0;
            *(sh8*)&As[nxt][row0+64][j8] = ra1;
            *(sh8*)&Bs[nxt][row0][j8]    = xshuf(rb0, u);
            *(sh8*)&Bs[nxt][row0+64][j8] = xshuf(rb1, u);
        }
        __syncthreads();
    }

    float ss = 0.f;
    size_t ob = (size_t)b*65536;
#pragma unroll
    for (int m = 0; m < 4; ++m) {
#pragma unroll
        for (int n = 0; n < 4; ++n) {
            f32x4 v = acc[m][n];
            int s0 = ti*128 + wm + m*16 + lg*4;
            int t0 = tj*128 + wn + n*16 + lr;
            float* op = out + ob + (size_t)s0*256 + t0;
#pragma unroll
            for (int r = 0; r < 4; ++r) {
                op[r*256] = v[r];
                ss += v[r]*v[r];
            }
            if (ti != tj) {   // mirror tile (1,0): C[t0][s0..s0+3] = v[0..3]
                *(float4*)(out + ob + (size_t)t0*256 + s0) =
                    make_float4(v[0], v[1], v[2], v[3]);
            }
        }
    }
    if (ti != tj) ss *= 2.f;   // off-diagonal counted twice in ||C||^2
#pragma unroll
    for (int o = 1; o < 64; o <<= 1) ss += __shfl_xor(ss, o);
    if (l == 0) wsum[w] = ss;
    __syncthreads();
    if (t == 0) atomicAdd(norm2 + b, wsum[0]+wsum[1]+wsum[2]+wsum[3]);
}

// ---------------- normalize rows ----------------
__global__ __launch_bounds__(256) void scale_kernel(
    float* __restrict__ out, const float* __restrict__ norm2)
{
    size_t i = (size_t)blockIdx.x * 256 + threadIdx.x;  // float4 index
    int b = (int)(i >> 14);
    float s = rsqrtf(norm2[b]);
    float4 v = ((const float4*)out)[i];
    v.x *= s; v.y *= s; v.z *= s; v.w *= s;
    ((float4*)out)[i] = v;
}

extern "C" void kernel_launch(void* const* d_in, const int* in_sizes, int n_in,
                              void* d_out, int out_size, void* d_ws, size_t ws_size,
                              hipStream_t stream)
{
    (void)in_sizes; (void)n_in;
    const float* x  = (const float*)d_in[0];
    const float* W1 = (const float*)d_in[1];
    const float* b1 = (const float*)d_in[2];
    const float* W2 = (const float*)d_in[3];
    const float* b2 = (const float*)d_in[4];
    const float* W3 = (const float*)d_in[5];
    const float* b3 = (const float*)d_in[6];
    float* out = (float*)d_out;

    // ---- workspace (peak 72 MB + 512 B) ----
    char* W = (char*)d_ws;
    const size_t MB = 1024*1024;
    unsigned short* LL  = (unsigned short*)(W + 0);      // bf16 [128][256][1024] 64MB
    unsigned short* P4n = (unsigned short*)(W + 64*MB);  // bf16 [128][16][1024]   4MB
    unsigned short* P4t = (unsigned short*)(W + 68*MB);  // bf16 [128][16][1024]   4MB
    float* nrm = (float*)(W + 72*MB);                    // f32 [128]
    const size_t NEED = 72*MB + 512;
    if (ws_size < NEED) {
        hipMemsetAsync(d_out, 0, (size_t)out_size * sizeof(float), stream);
        return;
    }

    enc_fused<<<BDIM, 256, 0, stream>>>(x, W1, b1, W2, b2, W3, b3, P4n, P4t, nrm);
    ll_mfma<<<dim3(16, BDIM), 256, 0, stream>>>(P4n, P4t, LL);
    pair_sym<<<dim3(3, BDIM), 256, 0, stream>>>(LL, out, nrm);
    scale_kernel<<<8192, 256, 0, stream>>>(out, nrm);
}